// Round 1
// baseline (133.548 us; speedup 1.0000x reference)
//
#include <hip/hip_runtime.h>

// ViT embed: patchify + linear + cls + posemb + LayerNorm, fused.
// images [128,3,224,224] f32 -> out [128,197,768] f32.
// M = 128*196 = 25088 patch-rows, K = 768, N = 768.

#define IMG_B 128
#define IMG_C 3
#define IMG_HW 224
#define NPATCH 14
#define DTOK 768
#define NTOK 197
#define MROWS 25088

typedef __attribute__((ext_vector_type(4))) float f32x4;
typedef __attribute__((ext_vector_type(8))) short bf16x8;
typedef __attribute__((ext_vector_type(4))) short bf16x4;

__device__ __forceinline__ unsigned short f2b(float f) {
  union { float f; unsigned u; } v; v.f = f;
  unsigned u = v.u;
  return (unsigned short)((u + 0x7fffu + ((u >> 16) & 1u)) >> 16);
}

// ---------------- setup kernels ----------------

__global__ void conv_w(const float* __restrict__ W, unsigned short* __restrict__ Wb) {
  int i = blockIdx.x * 256 + threadIdx.x;
  if (i < DTOK * DTOK) Wb[i] = f2b(W[i]);
}

// bpos[t][d] = pos(t,d) + (t==0 ? cls[d] : bias[d])
__global__ void make_bpos(const float* __restrict__ bias, const float* __restrict__ cls,
                          float* __restrict__ bpos) {
  int i = blockIdx.x * 256 + threadIdx.x;
  if (i >= NTOK * DTOK) return;
  int t = i / DTOK, d = i - (i / DTOK) * DTOK;
  float expo = (float)(d & ~1) * (1.0f / (float)DTOK);
  // 10000^expo = 2^(expo*log2(10000)); angle = t / 10000^expo
  float angle = (float)t * exp2f(-expo * 13.287712379549449f);
  float pv = (d & 1) ? cosf(angle) : sinf(angle);
  bpos[i] = pv + ((t == 0) ? cls[d] : bias[d]);
}

// token-0 row: LN(cls + pos[0]) broadcast to all 128 batches
__global__ __launch_bounds__(256) void cls_kernel(const float* __restrict__ bpos,
                                                  const float* __restrict__ gamma,
                                                  const float* __restrict__ beta,
                                                  float* __restrict__ out) {
  __shared__ float sred[8];
  const int tid = threadIdx.x;
  float v0 = bpos[tid], v1 = bpos[tid + 256], v2 = bpos[tid + 512];
  float s1 = v0 + v1 + v2;
  float s2 = v0 * v0 + v1 * v1 + v2 * v2;
  #pragma unroll
  for (int off = 32; off >= 1; off >>= 1) {
    s1 += __shfl_xor(s1, off, 64);
    s2 += __shfl_xor(s2, off, 64);
  }
  if ((tid & 63) == 0) { sred[(tid >> 6) * 2] = s1; sred[(tid >> 6) * 2 + 1] = s2; }
  __syncthreads();
  float S1 = sred[0] + sred[2] + sred[4] + sred[6];
  float S2 = sred[1] + sred[3] + sred[5] + sred[7];
  float mean = S1 * (1.0f / 768.0f);
  float rstd = rsqrtf(S2 * (1.0f / 768.0f) - mean * mean + 1e-5f);
  float o0 = (v0 - mean) * rstd * gamma[tid] + beta[tid];
  float o1 = (v1 - mean) * rstd * gamma[tid + 256] + beta[tid + 256];
  float o2 = (v2 - mean) * rstd * gamma[tid + 512] + beta[tid + 512];
  for (int b = 0; b < IMG_B; ++b) {
    float* op = out + (size_t)b * NTOK * DTOK;
    op[tid] = o0; op[tid + 256] = o1; op[tid + 512] = o2;
  }
}

// ---------------- main fused kernel ----------------
// block = 512 threads (8 waves). BM=64 rows, N=768 (full), BK=32, 24 k-iters.
// wave w owns cols [w*96, w*96+96): 4 m-frags x 6 n-frags of 16x16x32 MFMA.

__global__ __launch_bounds__(512) void vit_main(
    const float* __restrict__ images, const unsigned short* __restrict__ Wb,
    const float* __restrict__ bpos, const float* __restrict__ gamma,
    const float* __restrict__ beta, float* __restrict__ out) {
  __shared__ unsigned short Alds[64][40];  // stride 40 bf16: 2-way bank alias only (free)
  __shared__ float red[8][64][2];
  __shared__ float rowstat[64][2];

  const int tid = threadIdx.x;
  const int wid = tid >> 6;
  const int lane = tid & 63;
  const int l15 = lane & 15;
  const int g = lane >> 4;
  const int blk = blockIdx.x;
  const int cbase = wid * 96;

  // staging role: thread -> (row 0..63, k-quad 0..7)
  const int srow = tid >> 3;
  const int kq = tid & 7;
  const int kloc = kq * 4;
  const int sm = blk * 64 + srow;
  const int sb = sm / 196;
  const int sp = sm - sb * 196;
  const int spy = sp / 14, spx = sp - (sp / 14) * 14;
  const float* sbase =
      images + (size_t)sb * (IMG_C * IMG_HW * IMG_HW) + (spy * 16) * IMG_HW + spx * 16;

  f32x4 acc[4][6];
  #pragma unroll
  for (int mf = 0; mf < 4; ++mf)
    #pragma unroll
    for (int nf = 0; nf < 6; ++nf)
      acc[mf][nf] = (f32x4)(0.0f);

  for (int it = 0; it < 24; ++it) {
    const int k0 = it * 32;
    const int k = k0 + kloc;
    const int c = k >> 8;             // channel (BK=32 never crosses a channel)
    const int ph = (k & 255) >> 4;    // row inside patch
    const int pw = k & 15;            // col inside patch
    const float4 vv = *(const float4*)(sbase + c * (IMG_HW * IMG_HW) + ph * IMG_HW + pw);
    bf16x4 h;
    h[0] = (short)f2b(vv.x); h[1] = (short)f2b(vv.y);
    h[2] = (short)f2b(vv.z); h[3] = (short)f2b(vv.w);

    __syncthreads();                  // previous iter's frag reads done
    *(bf16x4*)&Alds[srow][kloc] = h;
    __syncthreads();                  // tile staged

    bf16x8 afr[4];
    #pragma unroll
    for (int mf = 0; mf < 4; ++mf)
      afr[mf] = *(const bf16x8*)&Alds[mf * 16 + l15][g * 8];

    bf16x8 bfr[6];
    #pragma unroll
    for (int nf = 0; nf < 6; ++nf)
      bfr[nf] = *(const bf16x8*)(Wb + (size_t)(cbase + nf * 16 + l15) * DTOK + k0 + g * 8);

    #pragma unroll
    for (int mf = 0; mf < 4; ++mf)
      #pragma unroll
      for (int nf = 0; nf < 6; ++nf)
        acc[mf][nf] =
            __builtin_amdgcn_mfma_f32_16x16x32_bf16(afr[mf], bfr[nf], acc[mf][nf], 0, 0, 0);
  }

  // ---- epilogue: +bias+pos, row LN over full 768 (all in-block) ----
  float s1[16], s2[16];
  #pragma unroll
  for (int mf = 0; mf < 4; ++mf) {
    #pragma unroll
    for (int r = 0; r < 4; ++r) {
      const int rl = mf * 16 + g * 4 + r;
      const int m = blk * 64 + rl;
      const int trow = 1 + (m % 196);
      const float* bp = bpos + (size_t)trow * DTOK + cbase + l15;
      float a1 = 0.f, a2 = 0.f;
      #pragma unroll
      for (int nf = 0; nf < 6; ++nf) {
        float val = acc[mf][nf][r] + bp[nf * 16];
        acc[mf][nf][r] = val;
        a1 += val; a2 += val * val;
      }
      s1[mf * 4 + r] = a1; s2[mf * 4 + r] = a2;
    }
  }
  #pragma unroll
  for (int off = 8; off >= 1; off >>= 1) {
    #pragma unroll
    for (int i = 0; i < 16; ++i) {
      s1[i] += __shfl_xor(s1[i], off, 64);
      s2[i] += __shfl_xor(s2[i], off, 64);
    }
  }
  if (l15 == 0) {
    #pragma unroll
    for (int mf = 0; mf < 4; ++mf)
      #pragma unroll
      for (int r = 0; r < 4; ++r) {
        const int rl = mf * 16 + g * 4 + r;
        red[wid][rl][0] = s1[mf * 4 + r];
        red[wid][rl][1] = s2[mf * 4 + r];
      }
  }
  __syncthreads();
  if (tid < 64) {
    float S1 = 0.f, S2 = 0.f;
    #pragma unroll
    for (int w = 0; w < 8; ++w) { S1 += red[w][tid][0]; S2 += red[w][tid][1]; }
    float mean = S1 * (1.0f / 768.0f);
    float var = S2 * (1.0f / 768.0f) - mean * mean;
    rowstat[tid][0] = mean;
    rowstat[tid][1] = rsqrtf(var + 1e-5f);
  }
  __syncthreads();

  float gm[6], bt[6];
  #pragma unroll
  for (int nf = 0; nf < 6; ++nf) {
    gm[nf] = gamma[cbase + nf * 16 + l15];
    bt[nf] = beta[cbase + nf * 16 + l15];
  }
  #pragma unroll
  for (int mf = 0; mf < 4; ++mf) {
    #pragma unroll
    for (int r = 0; r < 4; ++r) {
      const int rl = mf * 16 + g * 4 + r;
      const int m = blk * 64 + rl;
      const int bb = m / 196;
      const int orow = bb * 197 + 1 + (m - bb * 196);
      const float mean = rowstat[rl][0], rstd = rowstat[rl][1];
      float* op = out + (size_t)orow * DTOK + cbase + l15;
      #pragma unroll
      for (int nf = 0; nf < 6; ++nf)
        op[nf * 16] = (acc[mf][nf][r] - mean) * rstd * gm[nf] + bt[nf];
    }
  }
}

extern "C" void kernel_launch(void* const* d_in, const int* in_sizes, int n_in,
                              void* d_out, int out_size, void* d_ws, size_t ws_size,
                              hipStream_t stream) {
  const float* images = (const float*)d_in[0];
  const float* W      = (const float*)d_in[1];
  const float* bias   = (const float*)d_in[2];
  const float* cls    = (const float*)d_in[3];
  const float* gamma  = (const float*)d_in[4];
  const float* beta   = (const float*)d_in[5];
  float* out = (float*)d_out;

  unsigned short* Wb = (unsigned short*)d_ws;                       // 768*768*2 = 1179648 B
  float* bpos = (float*)((char*)d_ws + (size_t)DTOK * DTOK * 2);    // 197*768*4 = 605184 B

  conv_w<<<(DTOK * DTOK + 255) / 256, 256, 0, stream>>>(W, Wb);
  make_bpos<<<(NTOK * DTOK + 255) / 256, 256, 0, stream>>>(bias, cls, bpos);
  cls_kernel<<<1, 256, 0, stream>>>(bpos, gamma, beta, out);
  vit_main<<<MROWS / 64, 512, 0, stream>>>(images, Wb, bpos, gamma, beta, out);
}

// Round 2
// 107.115 us; speedup vs baseline: 1.2468x; 1.2468x over previous
//
#include <hip/hip_runtime.h>

// ViT embed: patchify + linear + cls + posemb + LayerNorm, fused.
// images [128,3,224,224] f32 -> out [128,197,768] f32.
// M = 128*196 = 25088 patch-rows, K = 768, N = 768.
// v2: software-pipelined K-loop — LDS A double-buffer (1 barrier/iter),
// depth-2 image reg prefetch, depth-1 B-frag reg double-buffer,
// raw s_barrier with lgkmcnt-only drain so global loads stay in flight.

#define IMG_B 128
#define IMG_C 3
#define IMG_HW 224
#define DTOK 768
#define NTOK 197
#define MROWS 25088

typedef __attribute__((ext_vector_type(4))) float f32x4;
typedef __attribute__((ext_vector_type(8))) short bf16x8;
typedef __attribute__((ext_vector_type(4))) short bf16x4;

__device__ __forceinline__ unsigned short f2b(float f) {
  union { float f; unsigned u; } v; v.f = f;
  unsigned u = v.u;
  return (unsigned short)((u + 0x7fffu + ((u >> 16) & 1u)) >> 16);
}

// ---------------- setup kernels ----------------

__global__ void conv_w(const float* __restrict__ W, unsigned short* __restrict__ Wb) {
  int i = blockIdx.x * 256 + threadIdx.x;
  if (i < DTOK * DTOK) Wb[i] = f2b(W[i]);
}

// bpos[t][d] = pos(t,d) + (t==0 ? cls[d] : bias[d])
__global__ void make_bpos(const float* __restrict__ bias, const float* __restrict__ cls,
                          float* __restrict__ bpos) {
  int i = blockIdx.x * 256 + threadIdx.x;
  if (i >= NTOK * DTOK) return;
  int t = i / DTOK, d = i - (i / DTOK) * DTOK;
  float expo = (float)(d & ~1) * (1.0f / (float)DTOK);
  float angle = (float)t * exp2f(-expo * 13.287712379549449f);
  float pv = (d & 1) ? cosf(angle) : sinf(angle);
  bpos[i] = pv + ((t == 0) ? cls[d] : bias[d]);
}

// token-0 row: LN(cls + pos[0]) broadcast to all 128 batches
__global__ __launch_bounds__(256) void cls_kernel(const float* __restrict__ bpos,
                                                  const float* __restrict__ gamma,
                                                  const float* __restrict__ beta,
                                                  float* __restrict__ out) {
  __shared__ float sred[8];
  const int tid = threadIdx.x;
  float v0 = bpos[tid], v1 = bpos[tid + 256], v2 = bpos[tid + 512];
  float s1 = v0 + v1 + v2;
  float s2 = v0 * v0 + v1 * v1 + v2 * v2;
  #pragma unroll
  for (int off = 32; off >= 1; off >>= 1) {
    s1 += __shfl_xor(s1, off, 64);
    s2 += __shfl_xor(s2, off, 64);
  }
  if ((tid & 63) == 0) { sred[(tid >> 6) * 2] = s1; sred[(tid >> 6) * 2 + 1] = s2; }
  __syncthreads();
  float S1 = sred[0] + sred[2] + sred[4] + sred[6];
  float S2 = sred[1] + sred[3] + sred[5] + sred[7];
  float mean = S1 * (1.0f / 768.0f);
  float rstd = rsqrtf(S2 * (1.0f / 768.0f) - mean * mean + 1e-5f);
  float o0 = (v0 - mean) * rstd * gamma[tid] + beta[tid];
  float o1 = (v1 - mean) * rstd * gamma[tid + 256] + beta[tid + 256];
  float o2 = (v2 - mean) * rstd * gamma[tid + 512] + beta[tid + 512];
  for (int b = 0; b < IMG_B; ++b) {
    float* op = out + (size_t)b * NTOK * DTOK;
    op[tid] = o0; op[tid + 256] = o1; op[tid + 512] = o2;
  }
}

// ---------------- main fused kernel ----------------
// block = 512 threads (8 waves). BM=64 rows, N=768 (full), BK=32, 24 k-iters.
// wave w owns cols [w*96, w*96+96): 4 m-frags x 6 n-frags of 16x16x32 MFMA.

__global__ __launch_bounds__(512) void vit_main(
    const float* __restrict__ images, const unsigned short* __restrict__ Wb,
    const float* __restrict__ bpos, const float* __restrict__ gamma,
    const float* __restrict__ beta, float* __restrict__ out) {
  // stride 40 shorts = 80B: 16B-aligned rows, read pattern 2-way bank alias (free)
  __shared__ unsigned short Alds[2][64][40];
  __shared__ float red[8][64][2];
  __shared__ float rowstat[64][2];

  const int tid = threadIdx.x;
  const int wid = tid >> 6;
  const int lane = tid & 63;
  const int l15 = lane & 15;
  const int g = lane >> 4;
  const int blk = blockIdx.x;
  const int cbase = wid * 96;

  // staging role: thread -> (row 0..63, k-quad 0..7)
  const int srow = tid >> 3;
  const int kq = tid & 7;
  const int kloc = kq * 4;
  const int sm = blk * 64 + srow;
  const int sb = sm / 196;
  const int sp = sm - sb * 196;
  const int spy = sp / 14, spx = sp - (sp / 14) * 14;
  // per-thread image base incl. intra-tile (kq) offset; tile it adds
  // (it>>3)*50176 + (it&7)*448 floats.
  const float* sbase2 = images + (size_t)sb * (IMG_C * IMG_HW * IMG_HW) +
                        (spy * 16) * IMG_HW + spx * 16 + (kq >> 2) * IMG_HW + (kq & 3) * 4;
  // per-lane B base: row (cbase+l15), k offset g*8
  const unsigned short* wbase = Wb + (size_t)(cbase + l15) * DTOK + g * 8;

  f32x4 acc[4][6];
  #pragma unroll
  for (int mf = 0; mf < 4; ++mf)
    #pragma unroll
    for (int nf = 0; nf < 6; ++nf)
      acc[mf][nf] = (f32x4)(0.0f);

  float4 rimg[2];       // tile t lives in rimg[t&1]
  bf16x8 bfr[2][6];     // tile t's B frags live in bfr[t&1]

  // ---- prologue: tiles 0,1 image loads; tile 0 B frags; stage tile 0 ----
  rimg[0] = *(const float4*)(sbase2);
  rimg[1] = *(const float4*)(sbase2 + 448);
  #pragma unroll
  for (int nf = 0; nf < 6; ++nf)
    bfr[0][nf] = *(const bf16x8*)(wbase + nf * 12288);
  {
    float4 rv = rimg[0];
    bf16x4 h;
    h[0] = (short)f2b(rv.x); h[1] = (short)f2b(rv.y);
    h[2] = (short)f2b(rv.z); h[3] = (short)f2b(rv.w);
    *(bf16x4*)&Alds[0][srow][kloc] = h;
  }
  asm volatile("s_waitcnt lgkmcnt(0)" ::: "memory");
  __builtin_amdgcn_s_barrier();
  asm volatile("" ::: "memory");

  // ---- pipelined K-loop: CUR is a literal (static reg-array indexing) ----
#define K_BODY(CUR, IT)                                                            \
  {                                                                                \
    if ((IT) + 2 < 24)                                                             \
      rimg[CUR] = *(const float4*)(sbase2 + (((IT) + 2) >> 3) * 50176 +            \
                                   (((IT) + 2) & 7) * 448);                        \
    if ((IT) + 1 < 24) {                                                           \
      _Pragma("unroll")                                                            \
      for (int nf = 0; nf < 6; ++nf)                                               \
        bfr[(CUR) ^ 1][nf] =                                                       \
            *(const bf16x8*)(wbase + nf * 12288 + ((IT) + 1) * 32);                \
    }                                                                              \
    bf16x8 afr[4];                                                                 \
    _Pragma("unroll")                                                              \
    for (int mf = 0; mf < 4; ++mf)                                                 \
      afr[mf] = *(const bf16x8*)&Alds[CUR][mf * 16 + l15][g * 8];                  \
    _Pragma("unroll")                                                              \
    for (int nf = 0; nf < 6; ++nf) {                                               \
      _Pragma("unroll")                                                            \
      for (int mf = 0; mf < 4; ++mf)                                               \
        acc[mf][nf] = __builtin_amdgcn_mfma_f32_16x16x32_bf16(                     \
            afr[mf], bfr[CUR][nf], acc[mf][nf], 0, 0, 0);                          \
    }                                                                              \
    if ((IT) + 1 < 24) {                                                           \
      float4 rv = rimg[(CUR) ^ 1];                                                 \
      bf16x4 h;                                                                    \
      h[0] = (short)f2b(rv.x); h[1] = (short)f2b(rv.y);                            \
      h[2] = (short)f2b(rv.z); h[3] = (short)f2b(rv.w);                            \
      *(bf16x4*)&Alds[(CUR) ^ 1][srow][kloc] = h;                                  \
    }                                                                              \
    asm volatile("s_waitcnt lgkmcnt(0)" ::: "memory");                             \
    __builtin_amdgcn_s_barrier();                                                  \
    asm volatile("" ::: "memory");                                                 \
  }

  for (int jt = 0; jt < 12; ++jt) {
    const int it = jt * 2;
    K_BODY(0, it)
    K_BODY(1, it + 1)
  }
#undef K_BODY

  // ---- epilogue: +bias+pos, row LN over full 768 (all in-block) ----
  float s1[16], s2[16];
  #pragma unroll
  for (int mf = 0; mf < 4; ++mf) {
    #pragma unroll
    for (int r = 0; r < 4; ++r) {
      const int rl = mf * 16 + g * 4 + r;
      const int m = blk * 64 + rl;
      const int trow = 1 + (m % 196);
      const float* bp = bpos + (size_t)trow * DTOK + cbase + l15;
      float a1 = 0.f, a2 = 0.f;
      #pragma unroll
      for (int nf = 0; nf < 6; ++nf) {
        float val = acc[mf][nf][r] + bp[nf * 16];
        acc[mf][nf][r] = val;
        a1 += val; a2 += val * val;
      }
      s1[mf * 4 + r] = a1; s2[mf * 4 + r] = a2;
    }
  }
  #pragma unroll
  for (int off = 8; off >= 1; off >>= 1) {
    #pragma unroll
    for (int i = 0; i < 16; ++i) {
      s1[i] += __shfl_xor(s1[i], off, 64);
      s2[i] += __shfl_xor(s2[i], off, 64);
    }
  }
  if (l15 == 0) {
    #pragma unroll
    for (int mf = 0; mf < 4; ++mf)
      #pragma unroll
      for (int r = 0; r < 4; ++r) {
        const int rl = mf * 16 + g * 4 + r;
        red[wid][rl][0] = s1[mf * 4 + r];
        red[wid][rl][1] = s2[mf * 4 + r];
      }
  }
  __syncthreads();
  if (tid < 64) {
    float S1 = 0.f, S2 = 0.f;
    #pragma unroll
    for (int w = 0; w < 8; ++w) { S1 += red[w][tid][0]; S2 += red[w][tid][1]; }
    float mean = S1 * (1.0f / 768.0f);
    float var = S2 * (1.0f / 768.0f) - mean * mean;
    rowstat[tid][0] = mean;
    rowstat[tid][1] = rsqrtf(var + 1e-5f);
  }
  __syncthreads();

  float gm[6], bt[6];
  #pragma unroll
  for (int nf = 0; nf < 6; ++nf) {
    gm[nf] = gamma[cbase + nf * 16 + l15];
    bt[nf] = beta[cbase + nf * 16 + l15];
  }
  #pragma unroll
  for (int mf = 0; mf < 4; ++mf) {
    #pragma unroll
    for (int r = 0; r < 4; ++r) {
      const int rl = mf * 16 + g * 4 + r;
      const int m = blk * 64 + rl;
      const int bb = m / 196;
      const int orow = bb * 197 + 1 + (m - bb * 196);
      const float mean = rowstat[rl][0], rstd = rowstat[rl][1];
      float* op = out + (size_t)orow * DTOK + cbase + l15;
      #pragma unroll
      for (int nf = 0; nf < 6; ++nf)
        op[nf * 16] = (acc[mf][nf][r] - mean) * rstd * gm[nf] + bt[nf];
    }
  }
}

extern "C" void kernel_launch(void* const* d_in, const int* in_sizes, int n_in,
                              void* d_out, int out_size, void* d_ws, size_t ws_size,
                              hipStream_t stream) {
  const float* images = (const float*)d_in[0];
  const float* W      = (const float*)d_in[1];
  const float* bias   = (const float*)d_in[2];
  const float* cls    = (const float*)d_in[3];
  const float* gamma  = (const float*)d_in[4];
  const float* beta   = (const float*)d_in[5];
  float* out = (float*)d_out;

  unsigned short* Wb = (unsigned short*)d_ws;                       // 768*768*2 B
  float* bpos = (float*)((char*)d_ws + (size_t)DTOK * DTOK * 2);    // 197*768*4 B

  conv_w<<<(DTOK * DTOK + 255) / 256, 256, 0, stream>>>(W, Wb);
  make_bpos<<<(NTOK * DTOK + 255) / 256, 256, 0, stream>>>(bias, cls, bpos);
  cls_kernel<<<1, 256, 0, stream>>>(bpos, gamma, beta, out);
  vit_main<<<MROWS / 64, 512, 0, stream>>>(images, Wb, bpos, gamma, beta, out);
}